// Round 16
// baseline (376.995 us; speedup 1.0000x reference)
//
#include <hip/hip_runtime.h>
#include <cstdint>
#include <cstddef>

typedef _Float16 h16;
typedef _Float16 h16x2 __attribute__((ext_vector_type(2)));
typedef _Float16 h16x4 __attribute__((ext_vector_type(4)));
typedef _Float16 h16x8 __attribute__((ext_vector_type(8)));
typedef float f32x4 __attribute__((ext_vector_type(4)));

typedef const uint32_t GU32 __attribute__((address_space(1)));
typedef uint32_t LU32 __attribute__((address_space(3)));

__device__ __forceinline__ void gload_lds16(const void* g, void* l) {
  __builtin_amdgcn_global_load_lds((GU32*)g, (LU32*)l, 16, 0, 0);
}

__device__ __forceinline__ float sigm(float x) { return 1.f / (1.f + __expf(-x)); }

// ---------------------------------------------------------------------------
// GEMM: C(M,N) = A(M,K) @ Bt(N,K)^T, fp16 in, fp32 acc (MFMA 16x16x32).
// (128*TM)x128 block tile, BK=32, 4 waves, global_load_lds w16, XCD swizzle,
// bank-conflict-free LDS reads (r14 XOR slot swizzle, conflicts 9.4M -> 0),
// depth-2 3-buffer pipeline (r15: counted vmcnt + raw barriers, +9%).
// r16: TM=2 for conv1/conv2 — wave tile 128x64 (acc 8x4), LDS-read reuse
// 32 -> 42.7 FLOP/B (r15 post-mortem: fragment reads pace the loop, not
// HBM).  GRU GEMMs stay TM=1 (M=2176 is x128 not x256).
// Weight switch at bm >= bmSwitch: part0 = NODE weights, part1 = EDGE.
// NY=2: blockIdx.y selects (A,C,weights) problem (gi vs gh).
// EPI: 2 = bias fp16; 3 = fp16 split-K partial (C + z*M*N);
//      4 = FUSED CONV1+MAXPOOL (pool-bundled im2col rows; relu(max4+bias)
//          scattered into conv2-im2col tap slots).
// DO NOT re-add: r12 AG row-gather (replay divergence, unrooted);
// r6 LDS-repack epilogue (29%/row slower).
// ---------------------------------------------------------------------------
struct GemmP {
  const h16* A[2];
  const h16* Bt[2][2];
  void* C[2];
  const float* bias[2][2];
  int M, N, K, nkt, bmSwitch;
};

template <int EPI, int NY, int TM>
__global__ __launch_bounds__(256) void gemm_bt(GemmP P) {
  constexpr int ASZ = 4096 * TM;        // A-tile h16 per buffer
  constexpr int BUF = ASZ + 4096;       // h16 per buffer
  const int y = (NY == 2) ? blockIdx.y : 0;
  __shared__ __align__(16) h16 SH[3 * BUF];
  const int tid = threadIdx.x;
  const int lane = tid & 63;
  const int w = tid >> 6;
  const int ntn = P.N >> 7;
  const int nwg = gridDim.x;
  const int q8 = nwg >> 3, r8 = nwg & 7;
  const int xcd = blockIdx.x & 7, loc = blockIdx.x >> 3;
  const int wg = (xcd < r8 ? xcd * (q8 + 1) : r8 * (q8 + 1) + (xcd - r8) * q8) + loc;
  const int bm = wg / ntn;
  const int bn = wg - bm * ntn;
  const int part = (bm >= P.bmSwitch) ? 1 : 0;
  const h16* __restrict__ A = P.A[y];
  const h16* __restrict__ Bt = P.Bt[y][part];
  const float* __restrict__ bias = P.bias[y][part];
  const long m0 = (long)bm * (128 * TM);
  const long n0 = (long)bn << 7;
  const int wm = w >> 1, wn = w & 1;

  f32x4 acc[4 * TM][4] = {};

  const int srow = (w << 4) + (lane >> 2);
  // bank-conflict fix: staging SOURCE column slot pre-permuted per lane;
  // reads de-permute (involution).  Buffers stay linear (rule 21).
  const int skoff = ((lane & 3) ^ ((lane >> 3) & 3)) << 3;
  const h16* Ag = A + (m0 + srow) * P.K + skoff;
  const h16* Bg = Bt + (n0 + srow) * P.K + skoff;
  const int lr = lane & 15;
  const int kg = lane >> 4;
  const int slotr = (kg ^ ((lr >> 1) & 3)) << 3;
  const int ardo = (wm * 64 * TM + lr) * 32 + slotr;
  const int brdo = ASZ + ((wn << 6) + lr) * 32 + slotr;

  auto stage = [&](int kt, int b) {
    const h16* a = Ag + (long)kt * 32;
    const h16* bp = Bg + (long)kt * 32;
    h16* asw = SH + b * BUF + (w << 9);
    h16* bsw = SH + b * BUF + ASZ + (w << 9);
#pragma unroll
    for (int r = 0; r < 2 * TM; ++r)
      gload_lds16(a + (long)(64 * r) * P.K, asw + 2048 * r);
    gload_lds16(bp, bsw);
    gload_lds16(bp + (long)64 * P.K, bsw + 2048);
  };

  const int kt0 = blockIdx.z * P.nkt;
  const int ktEnd = kt0 + P.nkt;  // nkt >= 8 for all launches
  stage(kt0, 0);
  stage(kt0 + 1, 1);
  int cur = 0;
  for (int kt = kt0; kt < ktEnd; ++kt) {
    if (kt + 1 < ktEnd) {
      // drain oldest stage: steady outstanding = 2L, wait to L (L=2TM+2)
      if constexpr (TM == 1)
        asm volatile("s_waitcnt vmcnt(4)" ::: "memory");
      else
        asm volatile("s_waitcnt vmcnt(6)" ::: "memory");
    } else {
      asm volatile("s_waitcnt vmcnt(0)" ::: "memory");
    }
    __builtin_amdgcn_s_barrier();  // all waves' stage(kt) visible
    const h16* ard = SH + cur * BUF + ardo;
    const h16* brd = SH + cur * BUF + brdo;
    h16x8 af[4 * TM], bfr[4];
#pragma unroll
    for (int f = 0; f < 4 * TM; ++f) af[f] = *(const h16x8*)(ard + (f << 9));
#pragma unroll
    for (int f = 0; f < 4; ++f) bfr[f] = *(const h16x8*)(brd + (f << 9));
#pragma unroll
    for (int fm = 0; fm < 4 * TM; ++fm)
#pragma unroll
      for (int fn = 0; fn < 4; ++fn)
        acc[fm][fn] = __builtin_amdgcn_mfma_f32_16x16x32_f16(af[fm], bfr[fn],
                                                             acc[fm][fn], 0, 0, 0);
    __builtin_amdgcn_s_barrier();  // all reads of buf[cur] done
    if (kt + 2 < ktEnd) {
      int nb = cur + 2;
      if (nb >= 3) nb -= 3;
      stage(kt + 2, nb);  // overwrites buf last read at iter kt-1: safe
    }
    ++cur;
    if (cur == 3) cur = 0;
  }

  if (EPI == 4) {
    // Fused maxpool + relu + conv2-im2col scatter (duplicated taps).
    h16* p2 = (h16*)P.C[y];
#pragma unroll
    for (int fm = 0; fm < 4 * TM; ++fm) {
      long rb = (m0 + wm * 64 * TM + (fm << 4) + (kg << 2)) >> 2;  // g*9+grp
      int g = (int)(rb / 9);
      int grp = (int)(rb - (long)g * 9);
      int yp = grp / 3, xp = grp - yp * 3;
#pragma unroll
      for (int fn = 0; fn < 4; ++fn) {
        long col = n0 + (wn << 6) + (fn << 4) + lr;
        f32x4 a = acc[fm][fn];
        float v = fmaxf(fmaxf(a[0], a[1]), fmaxf(a[2], a[3])) + bias[col];
        h16 hv = (h16)fmaxf(v, 0.f);
#pragma unroll
        for (int ky = 0; ky < 2; ++ky) {
          int py2 = yp - ky;
          if (py2 < 0 || py2 > 1) continue;
#pragma unroll
          for (int kx = 0; kx < 2; ++kx) {
            int px2 = xp - kx;
            if (px2 < 0 || px2 > 1) continue;
            p2[((long)g * 4 + py2 * 2 + px2) * 4096 + (ky * 2 + kx) * 1024 +
               col] = hv;
          }
        }
      }
    }
  } else {
    h16* Ch = (h16*)P.C[y];
    if (EPI == 3) Ch += (long)blockIdx.z * P.M * P.N;
#pragma unroll
    for (int fm = 0; fm < 4 * TM; ++fm)
#pragma unroll
      for (int fn = 0; fn < 4; ++fn)
#pragma unroll
        for (int j = 0; j < 4; ++j) {
          long row = m0 + wm * 64 * TM + (fm << 4) + (kg << 2) + j;
          long col = n0 + (wn << 6) + (fn << 4) + lr;
          float v = acc[fm][fn][j];
          if (EPI == 2) v += bias[col];
          Ch[row * P.N + col] = (h16)v;
        }
  }
}

// ---------------------------------------------------------------------------
// im2col for conv1 (LDS-staged): block per image; first nNode images from
// nSrc, rest from eSrc starting at e0.  Row order is POOL-BUNDLED:
// row = g*36 + (yp*3+xp)*4 + (dy*2+dx), spatial (py,px) = (2yp+dy, 2xp+dx);
// col k = ch*4 + ky*2 + kx.  (Enables the EPI=4 fused-pool epilogue.)
// ---------------------------------------------------------------------------
__global__ void im2col1_kernel(const float* __restrict__ nSrc,
                               const float* __restrict__ eSrc, int nNode,
                               int e0, h16* __restrict__ P) {
  __shared__ float xl[6272];
  const int g = blockIdx.x;
  const int tid = threadIdx.x;
  const float* src = (g < nNode) ? nSrc + (long)g * 6272
                                 : eSrc + (long)(e0 + g - nNode) * 6272;
  for (int i = tid; i < 6272; i += 256) xl[i] = src[i];
  __syncthreads();
  h16* dst = P + (long)g * 36 * 512;
  for (int item = tid; item < 36 * 64; item += 256) {
    int p = item >> 6;        // spatial position py*6+px
    int k8 = item & 63;       // channel pair
    int py = p / 6, px = p - py * 6;
    int yp = py >> 1, dy = py & 1, xp = px >> 1, dx = px & 1;
    int prow = ((yp * 3 + xp) << 2) + (dy << 1) + dx;  // bundled row
    h16x8 v;
#pragma unroll
    for (int ci = 0; ci < 2; ++ci) {
      int base = (k8 * 2 + ci) * 49 + py * 7 + px;
      v[ci * 4 + 0] = (h16)xl[base];
      v[ci * 4 + 1] = (h16)xl[base + 1];
      v[ci * 4 + 2] = (h16)xl[base + 7];
      v[ci * 4 + 3] = (h16)xl[base + 8];
    }
    *(h16x8*)(dst + (long)prow * 512 + k8 * 8) = v;
  }
}

// pool2 + bias + relu over nparts fp16 split-K partials -> concat feat rows.
__global__ void pool2_kernel(const h16* __restrict__ C2, long partStride,
                             int nparts, const float* __restrict__ biasN,
                             const float* __restrict__ biasE, int nNode,
                             int e0, h16* __restrict__ featc) {
  long idx = (long)blockIdx.x * 256 + threadIdx.x;  // grid: imgs*2
  int o = (int)(idx & 511);
  long g = idx >> 9;
  float s0 = 0, s1 = 0, s2 = 0, s3 = 0;
  for (int s = 0; s < nparts; ++s) {
    const h16* bp = C2 + (long)s * partStride + g * 2048 + o;
    s0 += (float)bp[0]; s1 += (float)bp[512];
    s2 += (float)bp[1024]; s3 += (float)bp[1536];
  }
  const float* bias = (g < nNode) ? biasN : biasE;
  long row = (g < nNode) ? g : 128 + e0 + (g - nNode);
  float v = fmaxf(fmaxf(s0, s1), fmaxf(s2, s3)) + bias[o];
  featc[row * 512 + o] = (h16)fmaxf(v, 0.f);
}

// GRU init (h = 0), vectorized 4 elems/thread: gi from 2 fp16 split-K
// partials + b_ih; gh = b_hh.  Grid 1088 x 256 (2176 rows x 128 j-quads).
__global__ void gru_init_kernel(const h16* __restrict__ giP, long PS,
                                const float* __restrict__ nbih,
                                const float* __restrict__ ebih,
                                const float* __restrict__ nbhh,
                                const float* __restrict__ ebhh,
                                float* __restrict__ h, h16* __restrict__ hb) {
  long idx = (long)blockIdx.x * 256 + threadIdx.x;  // 2176*128
  int j = (int)(idx & 127) << 2;
  long m = idx >> 7;
  const float* bih = (m < 128) ? nbih : ebih;
  const float* bhh = (m < 128) ? nbhh : ebhh;
  const h16* a = giP + m * 1536;
  const h16* a2 = a + PS;
  f32x4 ho;
  h16x4 hbo;
  h16x4 ar = *(const h16x4*)(a + j), a2r = *(const h16x4*)(a2 + j);
  h16x4 az = *(const h16x4*)(a + 512 + j), a2z = *(const h16x4*)(a2 + 512 + j);
  h16x4 an = *(const h16x4*)(a + 1024 + j), a2n = *(const h16x4*)(a2 + 1024 + j);
  f32x4 br = *(const f32x4*)(bih + j), bz = *(const f32x4*)(bih + 512 + j),
        bn = *(const f32x4*)(bih + 1024 + j);
  f32x4 hr = *(const f32x4*)(bhh + j), hz = *(const f32x4*)(bhh + 512 + j),
        hn = *(const f32x4*)(bhh + 1024 + j);
#pragma unroll
  for (int i = 0; i < 4; ++i) {
    float gr = (float)ar[i] + (float)a2r[i] + br[i];
    float gz = (float)az[i] + (float)a2z[i] + bz[i];
    float gn = (float)an[i] + (float)a2n[i] + bn[i];
    float r = sigm(gr + hr[i]);
    float z = sigm(gz + hz[i]);
    float n = tanhf(gn + r * hn[i]);
    float hv = (1.f - z) * n;
    ho[i] = hv;
    hbo[i] = (h16)hv;
  }
  *(f32x4*)(h + m * 512 + j) = ho;
  *(h16x4*)(hb + m * 512 + j) = hbo;
}

// GRU step, vectorized 4 elems/thread, from fp16 split-K partials.
// out != null (last iter): write d_out directly, skip h/hc update.
__global__ void gru_step_kernel(const h16* __restrict__ giP,
                                const h16* __restrict__ ghP, long PS,
                                const float* __restrict__ nbih,
                                const float* __restrict__ ebih,
                                const float* __restrict__ nbhh,
                                const float* __restrict__ ebhh,
                                float* __restrict__ h, h16* __restrict__ hb,
                                float* __restrict__ out) {
  long idx = (long)blockIdx.x * 256 + threadIdx.x;  // 2176*128
  int j = (int)(idx & 127) << 2;
  long m = idx >> 7;
  const float* bih = (m < 128) ? nbih : ebih;
  const float* bhh = (m < 128) ? nbhh : ebhh;
  const h16* a = giP + m * 1536;
  const h16* a2 = a + PS;
  const h16* b = ghP + m * 1536;
  const h16* b2 = b + PS;
  h16x4 ar = *(const h16x4*)(a + j), a2r = *(const h16x4*)(a2 + j);
  h16x4 az = *(const h16x4*)(a + 512 + j), a2z = *(const h16x4*)(a2 + 512 + j);
  h16x4 an = *(const h16x4*)(a + 1024 + j), a2n = *(const h16x4*)(a2 + 1024 + j);
  h16x4 cr = *(const h16x4*)(b + j), c2r = *(const h16x4*)(b2 + j);
  h16x4 cz = *(const h16x4*)(b + 512 + j), c2z = *(const h16x4*)(b2 + 512 + j);
  h16x4 cn = *(const h16x4*)(b + 1024 + j), c2n = *(const h16x4*)(b2 + 1024 + j);
  f32x4 br = *(const f32x4*)(bih + j), bz = *(const f32x4*)(bih + 512 + j),
        bnn = *(const f32x4*)(bih + 1024 + j);
  f32x4 dr = *(const f32x4*)(bhh + j), dz = *(const f32x4*)(bhh + 512 + j),
        dn = *(const f32x4*)(bhh + 1024 + j);
  f32x4 hold = *(const f32x4*)(h + m * 512 + j);
  f32x4 ho;
  h16x4 hbo;
#pragma unroll
  for (int i = 0; i < 4; ++i) {
    float gir = (float)ar[i] + (float)a2r[i] + br[i];
    float giz = (float)az[i] + (float)a2z[i] + bz[i];
    float gin = (float)an[i] + (float)a2n[i] + bnn[i];
    float ghr = (float)cr[i] + (float)c2r[i] + dr[i];
    float ghz = (float)cz[i] + (float)c2z[i] + dz[i];
    float ghn = (float)cn[i] + (float)c2n[i] + dn[i];
    float r = sigm(gir + ghr);
    float z = sigm(giz + ghz);
    float n = tanhf(gin + r * ghn);
    float hv = (1.f - z) * n + z * hold[i];
    ho[i] = hv;
    hbo[i] = (h16)hv;
  }
  if (out == nullptr) {
    *(f32x4*)(h + m * 512 + j) = ho;
    *(h16x4*)(hb + m * 512 + j) = hbo;
  } else {
    if (m < 64) *(f32x4*)(out + m * 512 + j) = ho;
    else if (m >= 128 && m < 2112)
      *(f32x4*)(out + 32768 + (m - 128) * 512 + j) = ho;
  }
}

// Message kernel: one wave per edge (re = b*992+e); reads fp16 state hc.
// Vectorized: lane owns elements [lane*8, lane*8+8).
__global__ void message_kernel(const h16* __restrict__ hc,
                               const int* __restrict__ eidx,
                               const float* __restrict__ wnp,
                               const float* __restrict__ wps,
                               const float* __restrict__ wpo,
                               h16* __restrict__ msgc,
                               h16* __restrict__ nm_e, int istride) {
  int re = blockIdx.x * 4 + (threadIdx.x >> 6);
  int lane = threadIdx.x & 63;
  int b = re / 992;
  int e = re - b * 992;
  long base = ((long)b * 992 + e) * 3;
  int s = eidx[(base + 1) * istride];
  int o = eidx[(base + 2) * istride];
  const int t0 = lane << 3;
  h16x8 nsv = *(const h16x8*)(hc + (long)(b * 32 + s) * 512 + t0);
  h16x8 nov = *(const h16x8*)(hc + (long)(b * 32 + o) * 512 + t0);
  h16x8 ehv = *(const h16x8*)(hc + (long)(128 + re) * 512 + t0);
  f32x4 wn0 = *(const f32x4*)(wnp + t0), wn1 = *(const f32x4*)(wnp + t0 + 4);
  f32x4 wn2 = *(const f32x4*)(wnp + 512 + t0), wn3 = *(const f32x4*)(wnp + 516 + t0);
  f32x4 ws0 = *(const f32x4*)(wps + t0), ws1 = *(const f32x4*)(wps + t0 + 4);
  f32x4 ws2 = *(const f32x4*)(wps + 512 + t0), ws3 = *(const f32x4*)(wps + 516 + t0);
  f32x4 wo0 = *(const f32x4*)(wpo + t0), wo1 = *(const f32x4*)(wpo + t0 + 4);
  f32x4 wo2 = *(const f32x4*)(wpo + 512 + t0), wo3 = *(const f32x4*)(wpo + 516 + t0);
  float dn = 0, ds = 0, dob = 0;
#pragma unroll
  for (int i = 0; i < 8; ++i) {
    float nsf = (float)nsv[i], nof = (float)nov[i], ehf = (float)ehv[i];
    float wnv = (i < 4) ? wn0[i] : wn1[i - 4];
    float wnev = (i < 4) ? wn2[i] : wn3[i - 4];
    float wsv = (i < 4) ? ws0[i] : ws1[i - 4];
    float wsev = (i < 4) ? ws2[i] : ws3[i - 4];
    float wov = (i < 4) ? wo0[i] : wo1[i - 4];
    float woev = (i < 4) ? wo2[i] : wo3[i - 4];
    dn += nsf * wnv + ehf * wnev;
    ds += nsf * wsv + ehf * wsev;
    dob += nof * wov + ehf * woev;
  }
#pragma unroll
  for (int off = 32; off; off >>= 1) {
    dn += __shfl_xor(dn, off);
    ds += __shfl_xor(ds, off);
    dob += __shfl_xor(dob, off);
  }
  float sn = sigm(dn), ss = sigm(ds), so = sigm(dob);
  h16x8 me, ne;
#pragma unroll
  for (int i = 0; i < 8; ++i) {
    me[i] = (h16)(ss * (float)nsv[i] + so * (float)nov[i]);
    ne[i] = (h16)(sn * (float)ehv[i]);
  }
  *(h16x8*)(msgc + (long)(128 + re) * 512 + t0) = me;
  *(h16x8*)(nm_e + (long)re * 512 + t0) = ne;
}

// Incidence build: per (b,n), ordered 31 subj then 31 obj edge ids (batch-local).
__global__ void incid_kernel(const int* __restrict__ eidx,
                             int* __restrict__ elist, int istride) {
  int w = (blockIdx.x << 2) + (threadIdx.x >> 6);  // 64 waves
  int lane = threadIdx.x & 63;
  int b = w >> 5, n = w & 31;
  const int* eb = eidx + (long)b * 992 * 3 * istride;
  int* dst = elist + w * 62;
  int bs = 0, bo = 0;
  for (int c = 0; c < 16; ++c) {
    int e = c * 64 + lane;
    bool v = e < 992;
    int s = v ? eb[(e * 3 + 1) * istride] : -1;
    int o = v ? eb[(e * 3 + 2) * istride] : -1;
    unsigned long long ms = __ballot(s == n);
    unsigned long long mo = __ballot(o == n);
    unsigned long long below = (1ull << lane) - 1ull;
    if (s == n) {
      int p = bs + __popcll(ms & below);
      if (p < 31) dst[p] = e;
    }
    if (o == n) {
      int p = bo + __popcll(mo & below);
      if (p < 31) dst[31 + p] = e;
    }
    bs += __popcll(ms);
    bo += __popcll(mo);
  }
  for (int i = bs + lane; i < 31; i += 64) dst[i] = -1;
  for (int i = bo + lane; i < 31; i += 64) dst[31 + i] = -1;
}

// Node-message gather via incidence lists -> msgc rows 0..63 (batch-local ids).
__global__ void gather_kernel(const h16* __restrict__ nm_e,
                              const int* __restrict__ elist,
                              h16* __restrict__ msgc) {
  int bn = blockIdx.x;  // 64
  int t = threadIdx.x;  // 256
  int b = bn >> 5;
  const int* lst = elist + bn * 62;
  const h16* nmb = nm_e + (long)b * 992 * 512;
  float a0 = 0.f, a1 = 0.f;
#pragma unroll 2
  for (int i = 0; i < 62; ++i) {
    int e = lst[i];
    if (e < 0) continue;
    h16x2 v = *(const h16x2*)(nmb + (long)e * 512 + t * 2);
    a0 += (float)v.x;
    a1 += (float)v.y;
  }
  h16* d = msgc + (long)bn * 512 + t * 2;
  d[0] = (h16)a0;
  d[1] = (h16)a1;
}

// Fused f32->fp16 conversion of all 8 weight mats, 4 elems/thread
// (f32x4 loads; W2's K-permute segment does 4 stride-4 gathers).
struct Cvt8 {
  const float* s[8];
  h16* d[8];
  long cum[9];
  int perm[8];
};
__global__ void cvt8_kernel(Cvt8 j) {
  long idx = ((long)blockIdx.x * 256 + threadIdx.x) * 4;
  if (idx >= j.cum[8]) return;
  int seg = 0;
  while (idx >= j.cum[seg + 1]) ++seg;
  long off = idx - j.cum[seg];  // multiple of 4; segments are too
  h16x4 o4;
  if (j.perm[seg]) {
    long o = off >> 12;
    long rest = off & 4095;
    long q = rest >> 10;
    long ch = rest & 1023;
    const float* s = j.s[seg] + o * 4096 + ch * 4 + q;
#pragma unroll
    for (int i = 0; i < 4; ++i) o4[i] = (h16)s[i * 4];
  } else {
    f32x4 v = *(const f32x4*)(j.s[seg] + off);
#pragma unroll
    for (int i = 0; i < 4; ++i) o4[i] = (h16)v[i];
  }
  *(h16x4*)(j.d[seg] + off) = o4;
}

__global__ void diag_kernel(float* out, int n, float v) {
  int i = blockIdx.x * 256 + threadIdx.x;
  if (i < n) out[i] = (i == 0) ? v : 0.f;
}

// ---------------------------------------------------------------------------
extern "C" void kernel_launch(void* const* d_in, const int* in_sizes, int n_in,
                              void* d_out, int out_size, void* d_ws,
                              size_t ws_size, hipStream_t stream) {
  const float* node_lat = (const float*)d_in[0];
  const float* edge_lat = (const float*)d_in[1];
  const int* eidx = (const int*)d_in[2];
  const float* ncw1 = (const float*)d_in[3];
  const float* ncb1 = (const float*)d_in[4];
  const float* ncw2 = (const float*)d_in[5];
  const float* ncb2 = (const float*)d_in[6];
  const float* ecw1 = (const float*)d_in[7];
  const float* ecb1 = (const float*)d_in[8];
  const float* ecw2 = (const float*)d_in[9];
  const float* ecb2 = (const float*)d_in[10];
  const float* nwih = (const float*)d_in[11];
  const float* nwhh = (const float*)d_in[12];
  const float* nbih = (const float*)d_in[13];
  const float* nbhh = (const float*)d_in[14];
  const float* ewih = (const float*)d_in[15];
  const float* ewhh = (const float*)d_in[16];
  const float* ebih = (const float*)d_in[17];
  const float* ebhh = (const float*)d_in[18];
  const float* wnp = (const float*)d_in[19];
  const float* wps = (const float*)d_in[20];
  const float* wpo = (const float*)d_in[21];

  const int istride = (in_sizes[2] == 2 * 992 * 3 * 2) ? 2 : 1;
  const long PS = 2176L * 1536;  // gru partial stride (elements)

  char* wsb = (char*)d_ws;
  size_t cur = 0;
  auto alloc = [&](size_t b) -> char* {
    char* p = wsb + cur;
    cur += (b + 255) & ~(size_t)255;
    return p;
  };

  // ---- fixed region (~27 MB); concat rows: node 0..127, edge 128..2175 ----
  h16* W1rn = (h16*)alloc(1024 * 512 * 2);
  h16* W1re = (h16*)alloc(1024 * 512 * 2);
  h16* W2rn = (h16*)alloc((size_t)512 * 4096 * 2);
  h16* W2re = (h16*)alloc((size_t)512 * 4096 * 2);
  h16* Wihn = (h16*)alloc(1536 * 512 * 2);
  h16* Whhn = (h16*)alloc(1536 * 512 * 2);
  h16* Wihe = (h16*)alloc(1536 * 512 * 2);
  h16* Whhe = (h16*)alloc(1536 * 512 * 2);
  h16* featc = (h16*)alloc((size_t)2176 * 512 * 2);
  float* h = (float*)alloc((size_t)2176 * 512 * 4);
  h16* hc = (h16*)alloc((size_t)2176 * 512 * 2);
  h16* msgc = (h16*)alloc((size_t)2176 * 512 * 2);
  h16* nm_e = (h16*)alloc((size_t)2048 * 512 * 2);
  int* elist = (int*)alloc(64 * 62 * 4);
  size_t fixedEnd = cur;

  // ---- plan (fused conv1+pool: no C1 buffer). merged => one conv2. ----
  struct Chunk { int imgs, nNode, e0; };
  Chunk plan[8];
  int nch = 0;
  bool merged = false;
  long m1max = 0, m2launch = 0;
  const size_t gruB = (size_t)4 * PS * 2;  // 2 problems x 2 K-parts, fp16
  for (int t = 0; t < 4 && !nch; ++t) {
    Chunk p[8];
    int n;
    bool mg;
    if (t == 0) {
      n = 1; mg = true;
      p[0] = {2048, 64, 0};
    } else if (t == 1) {
      n = 2; mg = true;
      p[0] = {1024, 64, 0};
      p[1] = {1024, 0, 960};
    } else if (t == 2) {
      n = 4; mg = true;
      p[0] = {512, 64, 0};
      for (int i = 1; i < 4; ++i) p[i] = {512, 0, 448 + 512 * (i - 1)};
    } else {
      n = 8; mg = false;
      p[0] = {256, 64, 0};
      for (int i = 1; i < 8; ++i) p[i] = {256, 0, 192 + 256 * (i - 1)};
    }
    long m1m = 0, m2m = 0, m2t = 0;
    for (int i = 0; i < n; ++i) {
      long m1 = (long)p[i].imgs * 36;  // multiples of 256 by construction
      long m2 = (long)p[i].imgs * 4;
      if (m1 > m1m) m1m = m1;
      if (m2 > m2m) m2m = m2;
      m2t += m2;
    }
    long m2l = mg ? m2t : m2m;
    size_t scr = (size_t)m1m * 1024;                         // P1 bytes
    if ((size_t)m2l * 8192 > scr) scr = (size_t)m2l * 8192;  // C2h (z=8) fp16
    if (gruB > scr) scr = gruB;
    size_t need = fixedEnd + ((scr + 255) & ~(size_t)255) +
                  (((size_t)m2l * 8192 + 255) & ~(size_t)255);  // P2
    if (need <= ws_size) {
      nch = n;
      merged = mg;
      for (int i = 0; i < n; ++i) plan[i] = p[i];
      m1max = m1m;
      m2launch = m2l;
    }
  }
  if (!nch) {
    diag_kernel<<<(out_size + 255) / 256, 256, 0, stream>>>(
        (float*)d_out, out_size, (float)((double)ws_size * 1e-6));
    return;
  }
  size_t scr1 = (size_t)m1max * 1024;
  if ((size_t)m2launch * 8192 > scr1) scr1 = (size_t)m2launch * 8192;
  if (gruB > scr1) scr1 = gruB;
  char* scr = alloc(scr1);
  h16* P1 = (h16*)scr;             // conv1 A
  h16* C2h = (h16*)scr;            // conv2 fp16 partials (alias, P1 dead)
  h16* giPart = (h16*)scr;         // gru fp16 partials (alias, after pool2)
  h16* ghPart = giPart + 2 * PS;
  h16* P2 = (h16*)alloc((size_t)m2launch * 8192);

  // ---- weight conversion ----
  Cvt8 cj;
  const float* srcs[8] = {ncw1, ecw1, ncw2, ecw2, nwih, nwhh, ewih, ewhh};
  h16* dsts[8] = {W1rn, W1re, W2rn, W2re, Wihn, Whhn, Wihe, Whhe};
  long sizes[8] = {1024 * 512, 1024 * 512, (long)512 * 4096, (long)512 * 4096,
                   1536 * 512, 1536 * 512, 1536 * 512, 1536 * 512};
  int perms[8] = {0, 0, 1, 1, 0, 0, 0, 0};
  long c = 0;
  for (int i = 0; i < 8; ++i) {
    cj.s[i] = srcs[i];
    cj.d[i] = dsts[i];
    cj.cum[i] = c;
    cj.perm[i] = perms[i];
    c += sizes[i];
  }
  cj.cum[8] = c;
  cvt8_kernel<<<(unsigned)((c / 4 + 255) / 256), 256, 0, stream>>>(cj);
  incid_kernel<<<16, 256, 0, stream>>>(eidx, elist, istride);

  // ---- CNN encoders: im2col -> fused conv1+pool (-> conv2 + pool2) ----
  long imgBase = 0;
  for (int ci = 0; ci < nch; ++ci) {
    const Chunk& K = plan[ci];
    long m1 = (long)K.imgs * 36;
    long m2 = (long)K.imgs * 4;
    int sw1 = (K.nNode * 36) >> 8;  // 256-row blocks (TM=2)
    int sw2 = (K.nNode * 4) >> 8;

    im2col1_kernel<<<(unsigned)K.imgs, 256, 0, stream>>>(node_lat, edge_lat,
                                                         K.nNode, K.e0, P1);

    GemmP g1 = {};
    g1.A[0] = P1;
    g1.Bt[0][0] = W1rn; g1.Bt[0][1] = W1re;
    g1.C[0] = P2 + (merged ? imgBase * 4 * 4096 : 0);
    g1.bias[0][0] = ncb1; g1.bias[0][1] = ecb1;
    g1.M = (int)m1; g1.N = 1024; g1.K = 512; g1.nkt = 16; g1.bmSwitch = sw1;
    gemm_bt<4, 1, 2><<<(unsigned)((m1 >> 8) * 8), 256, 0, stream>>>(g1);
    imgBase += K.imgs;

    if (!merged) {
      GemmP g2 = {};
      g2.A[0] = P2;
      g2.Bt[0][0] = W2rn; g2.Bt[0][1] = W2re;
      g2.C[0] = C2h;
      g2.M = (int)m2; g2.N = 512; g2.K = 4096; g2.nkt = 16; g2.bmSwitch = sw2;
      gemm_bt<3, 1, 2><<<dim3((unsigned)((m2 >> 8) * 4), 1, 8), 256, 0,
                         stream>>>(g2);
      pool2_kernel<<<(unsigned)(K.imgs * 2), 256, 0, stream>>>(
          C2h, m2 * 512L, 8, ncb2, ecb2, K.nNode, K.e0, featc);
    }
  }
  if (merged) {  // one conv2 + one pool2 over all chunks
    GemmP g2 = {};
    g2.A[0] = P2;
    g2.Bt[0][0] = W2rn; g2.Bt[0][1] = W2re;
    g2.C[0] = C2h;
    g2.M = (int)m2launch; g2.N = 512; g2.K = 4096; g2.nkt = 16;
    g2.bmSwitch = 1;  // node rows 0..255 = first 256-row block
    gemm_bt<3, 1, 2><<<dim3((unsigned)((m2launch >> 8) * 4), 1, 8), 256, 0,
                       stream>>>(g2);
    pool2_kernel<<<(unsigned)(2048 * 2), 256, 0, stream>>>(
        C2h, m2launch * 512L, 8, ncb2, ecb2, 64, 0, featc);
  }

  // ---- initial GRU (h = 0): gi fp16 partials (z=2) then combine ----
  {
    GemmP g = {};
    g.A[0] = featc;
    g.Bt[0][0] = Wihn; g.Bt[0][1] = Wihe;
    g.C[0] = giPart;
    g.M = 2176; g.N = 1536; g.K = 512; g.nkt = 8; g.bmSwitch = 1;
    gemm_bt<3, 1, 1><<<dim3(17 * 12, 1, 2), 256, 0, stream>>>(g);
  }
  gru_init_kernel<<<1088, 256, 0, stream>>>(giPart, PS, nbih, ebih, nbhh, ebhh,
                                            h, hc);

  // ---- 2 message-passing iterations (ref's 3rd iteration output is dead) ----
  for (int it = 0; it < 2; ++it) {
    message_kernel<<<496, 256, 0, stream>>>(hc, eidx, wnp, wps, wpo, msgc,
                                            nm_e, istride);
    gather_kernel<<<64, 256, 0, stream>>>(nm_e, elist, msgc);
    GemmP g = {};
    g.A[0] = msgc; g.A[1] = hc;
    g.Bt[0][0] = Wihn; g.Bt[0][1] = Wihe;
    g.Bt[1][0] = Whhn; g.Bt[1][1] = Whhe;
    g.C[0] = giPart; g.C[1] = ghPart;
    g.M = 2176; g.N = 1536; g.K = 512; g.nkt = 8; g.bmSwitch = 1;
    gemm_bt<3, 2, 1><<<dim3(17 * 12, 2, 2), 256, 0, stream>>>(g);
    gru_step_kernel<<<1088, 256, 0, stream>>>(
        giPart, ghPart, PS, nbih, ebih, nbhh, ebhh, h, hc,
        (it == 1) ? (float*)d_out : nullptr);
  }
}

// Round 17
// 320.147 us; speedup vs baseline: 1.1776x; 1.1776x over previous
//
#include <hip/hip_runtime.h>
#include <cstdint>
#include <cstddef>

typedef _Float16 h16;
typedef _Float16 h16x2 __attribute__((ext_vector_type(2)));
typedef _Float16 h16x4 __attribute__((ext_vector_type(4)));
typedef _Float16 h16x8 __attribute__((ext_vector_type(8)));
typedef float f32x4 __attribute__((ext_vector_type(4)));

typedef const uint32_t GU32 __attribute__((address_space(1)));
typedef uint32_t LU32 __attribute__((address_space(3)));

__device__ __forceinline__ void gload_lds16(const void* g, void* l) {
  __builtin_amdgcn_global_load_lds((GU32*)g, (LU32*)l, 16, 0, 0);
}

__device__ __forceinline__ float sigm(float x) { return 1.f / (1.f + __expf(-x)); }

// ---------------------------------------------------------------------------
// GEMM: C(M,N) = A(M,K) @ Bt(N,K)^T, fp16 in, fp32 acc (MFMA 16x16x32).
// 128x128 tile, BK=32, 4 waves, global_load_lds w16, XCD-bijective swizzle,
// bank-conflict-free LDS reads (r14 XOR slot swizzle; conflicts 9.4M -> 0),
// depth-2 3-buffer pipeline (r15: counted vmcnt + raw barriers, +9%).
// r16 POST-MORTEM (do not re-add): TM=2 256-row tile -> 72KB LDS + 268
// unified regs -> 2 waves/SIMD, occupancy 11%, conv1 111.6 -> 169.2 us.
// The 128^2 / 3-blocks-per-CU geometry is the sweet spot here.
// Also do not re-add: r12 AG row-gather (replay divergence, unrooted);
// r6 LDS-repack epilogue (29%/row slower).
// Weight switch at bm >= bmSwitch: part0 = NODE weights, part1 = EDGE.
// NY=2: blockIdx.y selects (A,C,weights) problem (gi vs gh).
// EPI: 2 = bias fp16; 3 = fp16 split-K partial (C + z*M*N);
//      4 = FUSED CONV1+MAXPOOL (pool-bundled im2col rows; relu(max4+bias)
//          scattered into conv2-im2col tap slots).
// ---------------------------------------------------------------------------
struct GemmP {
  const h16* A[2];
  const h16* Bt[2][2];
  void* C[2];
  const float* bias[2][2];
  int M, N, K, nkt, bmSwitch;
};

template <int EPI, int NY>
__global__ __launch_bounds__(256) void gemm_bt(GemmP P) {
  const int y = (NY == 2) ? blockIdx.y : 0;
  __shared__ __align__(16) h16 SH[24576];  // 3 x (As 4096 + Bs 4096)
  const int tid = threadIdx.x;
  const int lane = tid & 63;
  const int w = tid >> 6;
  const int ntn = P.N >> 7;
  const int nwg = gridDim.x;
  const int q8 = nwg >> 3, r8 = nwg & 7;
  const int xcd = blockIdx.x & 7, loc = blockIdx.x >> 3;
  const int wg = (xcd < r8 ? xcd * (q8 + 1) : r8 * (q8 + 1) + (xcd - r8) * q8) + loc;
  const int bm = wg / ntn;
  const int bn = wg - bm * ntn;
  const int part = (bm >= P.bmSwitch) ? 1 : 0;
  const h16* __restrict__ A = P.A[y];
  const h16* __restrict__ Bt = P.Bt[y][part];
  const float* __restrict__ bias = P.bias[y][part];
  const long m0 = (long)bm << 7;
  const long n0 = (long)bn << 7;
  const int wm = w >> 1, wn = w & 1;

  f32x4 acc[4][4] = {};

  const int srow = (w << 4) + (lane >> 2);
  // bank-conflict fix: staging SOURCE column slot pre-permuted per lane;
  // reads de-permute (involution).  Buffers stay linear (rule 21).
  const int skoff = ((lane & 3) ^ ((lane >> 3) & 3)) << 3;
  const h16* Ag = A + (m0 + srow) * P.K + skoff;
  const h16* Bg = Bt + (n0 + srow) * P.K + skoff;
  const int lr = lane & 15;
  const int kg = lane >> 4;
  const int slotr = (kg ^ ((lr >> 1) & 3)) << 3;
  const int ardo = ((wm << 6) + lr) * 32 + slotr;
  const int brdo = 4096 + ((wn << 6) + lr) * 32 + slotr;

  auto stage = [&](int kt, int b) {
    const h16* a = Ag + (long)kt * 32;
    const h16* bp = Bg + (long)kt * 32;
    h16* asw = SH + b * 8192 + (w << 9);
    h16* bsw = SH + b * 8192 + 4096 + (w << 9);
    gload_lds16(a, asw);
    gload_lds16(a + (long)64 * P.K, asw + 2048);
    gload_lds16(bp, bsw);
    gload_lds16(bp + (long)64 * P.K, bsw + 2048);
  };

  const int kt0 = blockIdx.z * P.nkt;
  const int ktEnd = kt0 + P.nkt;  // nkt >= 8 for all launches
  stage(kt0, 0);
  stage(kt0 + 1, 1);
  int cur = 0;
  for (int kt = kt0; kt < ktEnd; ++kt) {
    if (kt + 1 < ktEnd) {
      asm volatile("s_waitcnt vmcnt(4)" ::: "memory");  // stage(kt) landed
    } else {
      asm volatile("s_waitcnt vmcnt(0)" ::: "memory");
    }
    __builtin_amdgcn_s_barrier();  // all waves' stage(kt) visible
    const h16* ard = SH + cur * 8192 + ardo;
    const h16* brd = SH + cur * 8192 + brdo;
    h16x8 af[4], bfr[4];
#pragma unroll
    for (int f = 0; f < 4; ++f) {
      af[f] = *(const h16x8*)(ard + (f << 9));
      bfr[f] = *(const h16x8*)(brd + (f << 9));
    }
#pragma unroll
    for (int fm = 0; fm < 4; ++fm)
#pragma unroll
      for (int fn = 0; fn < 4; ++fn)
        acc[fm][fn] = __builtin_amdgcn_mfma_f32_16x16x32_f16(af[fm], bfr[fn],
                                                             acc[fm][fn], 0, 0, 0);
    __builtin_amdgcn_s_barrier();  // all reads of buf[cur] done
    if (kt + 2 < ktEnd) {
      int nb = cur + 2;
      if (nb >= 3) nb -= 3;
      stage(kt + 2, nb);  // overwrites buf last read at iter kt-1: safe
    }
    ++cur;
    if (cur == 3) cur = 0;
  }

  if (EPI == 4) {
    // Fused maxpool + relu + conv2-im2col scatter (duplicated taps).
    h16* p2 = (h16*)P.C[y];
#pragma unroll
    for (int fm = 0; fm < 4; ++fm) {
      long rb = (m0 + (wm << 6) + (fm << 4) + (kg << 2)) >> 2;  // g*9 + grp
      int g = (int)(rb / 9);
      int grp = (int)(rb - (long)g * 9);
      int yp = grp / 3, xp = grp - yp * 3;
#pragma unroll
      for (int fn = 0; fn < 4; ++fn) {
        long col = n0 + (wn << 6) + (fn << 4) + lr;
        f32x4 a = acc[fm][fn];
        float v = fmaxf(fmaxf(a[0], a[1]), fmaxf(a[2], a[3])) + bias[col];
        h16 hv = (h16)fmaxf(v, 0.f);
#pragma unroll
        for (int ky = 0; ky < 2; ++ky) {
          int py2 = yp - ky;
          if (py2 < 0 || py2 > 1) continue;
#pragma unroll
          for (int kx = 0; kx < 2; ++kx) {
            int px2 = xp - kx;
            if (px2 < 0 || px2 > 1) continue;
            p2[((long)g * 4 + py2 * 2 + px2) * 4096 + (ky * 2 + kx) * 1024 +
               col] = hv;
          }
        }
      }
    }
  } else {
    h16* Ch = (h16*)P.C[y];
    if (EPI == 3) Ch += (long)blockIdx.z * P.M * P.N;
#pragma unroll
    for (int fm = 0; fm < 4; ++fm)
#pragma unroll
      for (int fn = 0; fn < 4; ++fn)
#pragma unroll
        for (int j = 0; j < 4; ++j) {
          long row = m0 + (wm << 6) + (fm << 4) + (kg << 2) + j;
          long col = n0 + (wn << 6) + (fn << 4) + lr;
          float v = acc[fm][fn][j];
          if (EPI == 2) v += bias[col];
          Ch[row * P.N + col] = (h16)v;
        }
  }
}

// ---------------------------------------------------------------------------
// im2col for conv1 (LDS-staged): block per image; first nNode images from
// nSrc, rest from eSrc starting at e0.  Row order is POOL-BUNDLED:
// row = g*36 + (yp*3+xp)*4 + (dy*2+dx), spatial (py,px) = (2yp+dy, 2xp+dx);
// col k = ch*4 + ky*2 + kx.  (Enables the EPI=4 fused-pool epilogue.)
// ---------------------------------------------------------------------------
__global__ void im2col1_kernel(const float* __restrict__ nSrc,
                               const float* __restrict__ eSrc, int nNode,
                               int e0, h16* __restrict__ P) {
  __shared__ float xl[6272];
  const int g = blockIdx.x;
  const int tid = threadIdx.x;
  const float* src = (g < nNode) ? nSrc + (long)g * 6272
                                 : eSrc + (long)(e0 + g - nNode) * 6272;
  for (int i = tid; i < 6272; i += 256) xl[i] = src[i];
  __syncthreads();
  h16* dst = P + (long)g * 36 * 512;
  for (int item = tid; item < 36 * 64; item += 256) {
    int p = item >> 6;        // spatial position py*6+px
    int k8 = item & 63;       // channel pair
    int py = p / 6, px = p - py * 6;
    int yp = py >> 1, dy = py & 1, xp = px >> 1, dx = px & 1;
    int prow = ((yp * 3 + xp) << 2) + (dy << 1) + dx;  // bundled row
    h16x8 v;
#pragma unroll
    for (int ci = 0; ci < 2; ++ci) {
      int base = (k8 * 2 + ci) * 49 + py * 7 + px;
      v[ci * 4 + 0] = (h16)xl[base];
      v[ci * 4 + 1] = (h16)xl[base + 1];
      v[ci * 4 + 2] = (h16)xl[base + 7];
      v[ci * 4 + 3] = (h16)xl[base + 8];
    }
    *(h16x8*)(dst + (long)prow * 512 + k8 * 8) = v;
  }
}

// pool2 + bias + relu over nparts fp16 split-K partials -> concat feat rows.
__global__ void pool2_kernel(const h16* __restrict__ C2, long partStride,
                             int nparts, const float* __restrict__ biasN,
                             const float* __restrict__ biasE, int nNode,
                             int e0, h16* __restrict__ featc) {
  long idx = (long)blockIdx.x * 256 + threadIdx.x;  // grid: imgs*2
  int o = (int)(idx & 511);
  long g = idx >> 9;
  float s0 = 0, s1 = 0, s2 = 0, s3 = 0;
  for (int s = 0; s < nparts; ++s) {
    const h16* bp = C2 + (long)s * partStride + g * 2048 + o;
    s0 += (float)bp[0]; s1 += (float)bp[512];
    s2 += (float)bp[1024]; s3 += (float)bp[1536];
  }
  const float* bias = (g < nNode) ? biasN : biasE;
  long row = (g < nNode) ? g : 128 + e0 + (g - nNode);
  float v = fmaxf(fmaxf(s0, s1), fmaxf(s2, s3)) + bias[o];
  featc[row * 512 + o] = (h16)fmaxf(v, 0.f);
}

// GRU init (h = 0), vectorized 4 elems/thread: gi from 2 fp16 split-K
// partials + b_ih; gh = b_hh.  Grid 1088 x 256 (2176 rows x 128 j-quads).
__global__ void gru_init_kernel(const h16* __restrict__ giP, long PS,
                                const float* __restrict__ nbih,
                                const float* __restrict__ ebih,
                                const float* __restrict__ nbhh,
                                const float* __restrict__ ebhh,
                                float* __restrict__ h, h16* __restrict__ hb) {
  long idx = (long)blockIdx.x * 256 + threadIdx.x;  // 2176*128
  int j = (int)(idx & 127) << 2;
  long m = idx >> 7;
  const float* bih = (m < 128) ? nbih : ebih;
  const float* bhh = (m < 128) ? nbhh : ebhh;
  const h16* a = giP + m * 1536;
  const h16* a2 = a + PS;
  f32x4 ho;
  h16x4 hbo;
  h16x4 ar = *(const h16x4*)(a + j), a2r = *(const h16x4*)(a2 + j);
  h16x4 az = *(const h16x4*)(a + 512 + j), a2z = *(const h16x4*)(a2 + 512 + j);
  h16x4 an = *(const h16x4*)(a + 1024 + j), a2n = *(const h16x4*)(a2 + 1024 + j);
  f32x4 br = *(const f32x4*)(bih + j), bz = *(const f32x4*)(bih + 512 + j),
        bn = *(const f32x4*)(bih + 1024 + j);
  f32x4 hr = *(const f32x4*)(bhh + j), hz = *(const f32x4*)(bhh + 512 + j),
        hn = *(const f32x4*)(bhh + 1024 + j);
#pragma unroll
  for (int i = 0; i < 4; ++i) {
    float gr = (float)ar[i] + (float)a2r[i] + br[i];
    float gz = (float)az[i] + (float)a2z[i] + bz[i];
    float gn = (float)an[i] + (float)a2n[i] + bn[i];
    float r = sigm(gr + hr[i]);
    float z = sigm(gz + hz[i]);
    float n = tanhf(gn + r * hn[i]);
    float hv = (1.f - z) * n;
    ho[i] = hv;
    hbo[i] = (h16)hv;
  }
  *(f32x4*)(h + m * 512 + j) = ho;
  *(h16x4*)(hb + m * 512 + j) = hbo;
}

// GRU step, vectorized 4 elems/thread, from fp16 split-K partials.
// out != null (last iter): write d_out directly, skip h/hc update.
__global__ void gru_step_kernel(const h16* __restrict__ giP,
                                const h16* __restrict__ ghP, long PS,
                                const float* __restrict__ nbih,
                                const float* __restrict__ ebih,
                                const float* __restrict__ nbhh,
                                const float* __restrict__ ebhh,
                                float* __restrict__ h, h16* __restrict__ hb,
                                float* __restrict__ out) {
  long idx = (long)blockIdx.x * 256 + threadIdx.x;  // 2176*128
  int j = (int)(idx & 127) << 2;
  long m = idx >> 7;
  const float* bih = (m < 128) ? nbih : ebih;
  const float* bhh = (m < 128) ? nbhh : ebhh;
  const h16* a = giP + m * 1536;
  const h16* a2 = a + PS;
  const h16* b = ghP + m * 1536;
  const h16* b2 = b + PS;
  h16x4 ar = *(const h16x4*)(a + j), a2r = *(const h16x4*)(a2 + j);
  h16x4 az = *(const h16x4*)(a + 512 + j), a2z = *(const h16x4*)(a2 + 512 + j);
  h16x4 an = *(const h16x4*)(a + 1024 + j), a2n = *(const h16x4*)(a2 + 1024 + j);
  h16x4 cr = *(const h16x4*)(b + j), c2r = *(const h16x4*)(b2 + j);
  h16x4 cz = *(const h16x4*)(b + 512 + j), c2z = *(const h16x4*)(b2 + 512 + j);
  h16x4 cn = *(const h16x4*)(b + 1024 + j), c2n = *(const h16x4*)(b2 + 1024 + j);
  f32x4 br = *(const f32x4*)(bih + j), bz = *(const f32x4*)(bih + 512 + j),
        bnn = *(const f32x4*)(bih + 1024 + j);
  f32x4 dr = *(const f32x4*)(bhh + j), dz = *(const f32x4*)(bhh + 512 + j),
        dn = *(const f32x4*)(bhh + 1024 + j);
  f32x4 hold = *(const f32x4*)(h + m * 512 + j);
  f32x4 ho;
  h16x4 hbo;
#pragma unroll
  for (int i = 0; i < 4; ++i) {
    float gir = (float)ar[i] + (float)a2r[i] + br[i];
    float giz = (float)az[i] + (float)a2z[i] + bz[i];
    float gin = (float)an[i] + (float)a2n[i] + bnn[i];
    float ghr = (float)cr[i] + (float)c2r[i] + dr[i];
    float ghz = (float)cz[i] + (float)c2z[i] + dz[i];
    float ghn = (float)cn[i] + (float)c2n[i] + dn[i];
    float r = sigm(gir + ghr);
    float z = sigm(giz + ghz);
    float n = tanhf(gin + r * ghn);
    float hv = (1.f - z) * n + z * hold[i];
    ho[i] = hv;
    hbo[i] = (h16)hv;
  }
  if (out == nullptr) {
    *(f32x4*)(h + m * 512 + j) = ho;
    *(h16x4*)(hb + m * 512 + j) = hbo;
  } else {
    if (m < 64) *(f32x4*)(out + m * 512 + j) = ho;
    else if (m >= 128 && m < 2112)
      *(f32x4*)(out + 32768 + (m - 128) * 512 + j) = ho;
  }
}

// Message kernel: one wave per edge (re = b*992+e); reads fp16 state hc.
// Vectorized: lane owns elements [lane*8, lane*8+8).
__global__ void message_kernel(const h16* __restrict__ hc,
                               const int* __restrict__ eidx,
                               const float* __restrict__ wnp,
                               const float* __restrict__ wps,
                               const float* __restrict__ wpo,
                               h16* __restrict__ msgc,
                               h16* __restrict__ nm_e, int istride) {
  int re = blockIdx.x * 4 + (threadIdx.x >> 6);
  int lane = threadIdx.x & 63;
  int b = re / 992;
  int e = re - b * 992;
  long base = ((long)b * 992 + e) * 3;
  int s = eidx[(base + 1) * istride];
  int o = eidx[(base + 2) * istride];
  const int t0 = lane << 3;
  h16x8 nsv = *(const h16x8*)(hc + (long)(b * 32 + s) * 512 + t0);
  h16x8 nov = *(const h16x8*)(hc + (long)(b * 32 + o) * 512 + t0);
  h16x8 ehv = *(const h16x8*)(hc + (long)(128 + re) * 512 + t0);
  f32x4 wn0 = *(const f32x4*)(wnp + t0), wn1 = *(const f32x4*)(wnp + t0 + 4);
  f32x4 wn2 = *(const f32x4*)(wnp + 512 + t0), wn3 = *(const f32x4*)(wnp + 516 + t0);
  f32x4 ws0 = *(const f32x4*)(wps + t0), ws1 = *(const f32x4*)(wps + t0 + 4);
  f32x4 ws2 = *(const f32x4*)(wps + 512 + t0), ws3 = *(const f32x4*)(wps + 516 + t0);
  f32x4 wo0 = *(const f32x4*)(wpo + t0), wo1 = *(const f32x4*)(wpo + t0 + 4);
  f32x4 wo2 = *(const f32x4*)(wpo + 512 + t0), wo3 = *(const f32x4*)(wpo + 516 + t0);
  float dn = 0, ds = 0, dob = 0;
#pragma unroll
  for (int i = 0; i < 8; ++i) {
    float nsf = (float)nsv[i], nof = (float)nov[i], ehf = (float)ehv[i];
    float wnv = (i < 4) ? wn0[i] : wn1[i - 4];
    float wnev = (i < 4) ? wn2[i] : wn3[i - 4];
    float wsv = (i < 4) ? ws0[i] : ws1[i - 4];
    float wsev = (i < 4) ? ws2[i] : ws3[i - 4];
    float wov = (i < 4) ? wo0[i] : wo1[i - 4];
    float woev = (i < 4) ? wo2[i] : wo3[i - 4];
    dn += nsf * wnv + ehf * wnev;
    ds += nsf * wsv + ehf * wsev;
    dob += nof * wov + ehf * woev;
  }
#pragma unroll
  for (int off = 32; off; off >>= 1) {
    dn += __shfl_xor(dn, off);
    ds += __shfl_xor(ds, off);
    dob += __shfl_xor(dob, off);
  }
  float sn = sigm(dn), ss = sigm(ds), so = sigm(dob);
  h16x8 me, ne;
#pragma unroll
  for (int i = 0; i < 8; ++i) {
    me[i] = (h16)(ss * (float)nsv[i] + so * (float)nov[i]);
    ne[i] = (h16)(sn * (float)ehv[i]);
  }
  *(h16x8*)(msgc + (long)(128 + re) * 512 + t0) = me;
  *(h16x8*)(nm_e + (long)re * 512 + t0) = ne;
}

// Incidence build: per (b,n), ordered 31 subj then 31 obj edge ids (batch-local).
__global__ void incid_kernel(const int* __restrict__ eidx,
                             int* __restrict__ elist, int istride) {
  int w = (blockIdx.x << 2) + (threadIdx.x >> 6);  // 64 waves
  int lane = threadIdx.x & 63;
  int b = w >> 5, n = w & 31;
  const int* eb = eidx + (long)b * 992 * 3 * istride;
  int* dst = elist + w * 62;
  int bs = 0, bo = 0;
  for (int c = 0; c < 16; ++c) {
    int e = c * 64 + lane;
    bool v = e < 992;
    int s = v ? eb[(e * 3 + 1) * istride] : -1;
    int o = v ? eb[(e * 3 + 2) * istride] : -1;
    unsigned long long ms = __ballot(s == n);
    unsigned long long mo = __ballot(o == n);
    unsigned long long below = (1ull << lane) - 1ull;
    if (s == n) {
      int p = bs + __popcll(ms & below);
      if (p < 31) dst[p] = e;
    }
    if (o == n) {
      int p = bo + __popcll(mo & below);
      if (p < 31) dst[31 + p] = e;
    }
    bs += __popcll(ms);
    bo += __popcll(mo);
  }
  for (int i = bs + lane; i < 31; i += 64) dst[i] = -1;
  for (int i = bo + lane; i < 31; i += 64) dst[31 + i] = -1;
}

// Node-message gather via incidence lists -> msgc rows 0..63 (batch-local ids).
__global__ void gather_kernel(const h16* __restrict__ nm_e,
                              const int* __restrict__ elist,
                              h16* __restrict__ msgc) {
  int bn = blockIdx.x;  // 64
  int t = threadIdx.x;  // 256
  int b = bn >> 5;
  const int* lst = elist + bn * 62;
  const h16* nmb = nm_e + (long)b * 992 * 512;
  float a0 = 0.f, a1 = 0.f;
#pragma unroll 2
  for (int i = 0; i < 62; ++i) {
    int e = lst[i];
    if (e < 0) continue;
    h16x2 v = *(const h16x2*)(nmb + (long)e * 512 + t * 2);
    a0 += (float)v.x;
    a1 += (float)v.y;
  }
  h16* d = msgc + (long)bn * 512 + t * 2;
  d[0] = (h16)a0;
  d[1] = (h16)a1;
}

// Fused f32->fp16 conversion of all 8 weight mats, 4 elems/thread
// (f32x4 loads; W2's K-permute segment does 4 stride-4 gathers).
struct Cvt8 {
  const float* s[8];
  h16* d[8];
  long cum[9];
  int perm[8];
};
__global__ void cvt8_kernel(Cvt8 j) {
  long idx = ((long)blockIdx.x * 256 + threadIdx.x) * 4;
  if (idx >= j.cum[8]) return;
  int seg = 0;
  while (idx >= j.cum[seg + 1]) ++seg;
  long off = idx - j.cum[seg];  // multiple of 4; segments are too
  h16x4 o4;
  if (j.perm[seg]) {
    long o = off >> 12;
    long rest = off & 4095;
    long q = rest >> 10;
    long ch = rest & 1023;
    const float* s = j.s[seg] + o * 4096 + ch * 4 + q;
#pragma unroll
    for (int i = 0; i < 4; ++i) o4[i] = (h16)s[i * 4];
  } else {
    f32x4 v = *(const f32x4*)(j.s[seg] + off);
#pragma unroll
    for (int i = 0; i < 4; ++i) o4[i] = (h16)v[i];
  }
  *(h16x4*)(j.d[seg] + off) = o4;
}

__global__ void diag_kernel(float* out, int n, float v) {
  int i = blockIdx.x * 256 + threadIdx.x;
  if (i < n) out[i] = (i == 0) ? v : 0.f;
}

// ---------------------------------------------------------------------------
extern "C" void kernel_launch(void* const* d_in, const int* in_sizes, int n_in,
                              void* d_out, int out_size, void* d_ws,
                              size_t ws_size, hipStream_t stream) {
  const float* node_lat = (const float*)d_in[0];
  const float* edge_lat = (const float*)d_in[1];
  const int* eidx = (const int*)d_in[2];
  const float* ncw1 = (const float*)d_in[3];
  const float* ncb1 = (const float*)d_in[4];
  const float* ncw2 = (const float*)d_in[5];
  const float* ncb2 = (const float*)d_in[6];
  const float* ecw1 = (const float*)d_in[7];
  const float* ecb1 = (const float*)d_in[8];
  const float* ecw2 = (const float*)d_in[9];
  const float* ecb2 = (const float*)d_in[10];
  const float* nwih = (const float*)d_in[11];
  const float* nwhh = (const float*)d_in[12];
  const float* nbih = (const float*)d_in[13];
  const float* nbhh = (const float*)d_in[14];
  const float* ewih = (const float*)d_in[15];
  const float* ewhh = (const float*)d_in[16];
  const float* ebih = (const float*)d_in[17];
  const float* ebhh = (const float*)d_in[18];
  const float* wnp = (const float*)d_in[19];
  const float* wps = (const float*)d_in[20];
  const float* wpo = (const float*)d_in[21];

  const int istride = (in_sizes[2] == 2 * 992 * 3 * 2) ? 2 : 1;
  const long PS = 2176L * 1536;  // gru partial stride (elements)

  char* wsb = (char*)d_ws;
  size_t cur = 0;
  auto alloc = [&](size_t b) -> char* {
    char* p = wsb + cur;
    cur += (b + 255) & ~(size_t)255;
    return p;
  };

  // ---- fixed region (~27 MB); concat rows: node 0..127, edge 128..2175 ----
  h16* W1rn = (h16*)alloc(1024 * 512 * 2);
  h16* W1re = (h16*)alloc(1024 * 512 * 2);
  h16* W2rn = (h16*)alloc((size_t)512 * 4096 * 2);
  h16* W2re = (h16*)alloc((size_t)512 * 4096 * 2);
  h16* Wihn = (h16*)alloc(1536 * 512 * 2);
  h16* Whhn = (h16*)alloc(1536 * 512 * 2);
  h16* Wihe = (h16*)alloc(1536 * 512 * 2);
  h16* Whhe = (h16*)alloc(1536 * 512 * 2);
  h16* featc = (h16*)alloc((size_t)2176 * 512 * 2);
  float* h = (float*)alloc((size_t)2176 * 512 * 4);
  h16* hc = (h16*)alloc((size_t)2176 * 512 * 2);
  h16* msgc = (h16*)alloc((size_t)2176 * 512 * 2);
  h16* nm_e = (h16*)alloc((size_t)2048 * 512 * 2);
  int* elist = (int*)alloc(64 * 62 * 4);
  size_t fixedEnd = cur;

  // ---- plan (fused conv1+pool: no C1 buffer). merged => one conv2. ----
  struct Chunk { int imgs, nNode, e0; };
  Chunk plan[8];
  int nch = 0;
  bool merged = false;
  long m1max = 0, m2launch = 0;
  const size_t gruB = (size_t)4 * PS * 2;  // 2 problems x 2 K-parts, fp16
  for (int t = 0; t < 4 && !nch; ++t) {
    Chunk p[8];
    int n;
    bool mg;
    if (t == 0) {
      n = 1; mg = true;
      p[0] = {2048, 64, 0};
    } else if (t == 1) {
      n = 2; mg = true;
      p[0] = {1024, 64, 0};
      p[1] = {1024, 0, 960};
    } else if (t == 2) {
      n = 4; mg = true;
      p[0] = {512, 64, 0};
      for (int i = 1; i < 4; ++i) p[i] = {512, 0, 448 + 512 * (i - 1)};
    } else {
      n = 8; mg = false;
      p[0] = {256, 64, 0};
      for (int i = 1; i < 8; ++i) p[i] = {256, 0, 192 + 256 * (i - 1)};
    }
    long m1m = 0, m2m = 0, m2t = 0;
    for (int i = 0; i < n; ++i) {
      long m1 = (long)p[i].imgs * 36;  // multiples of 128 by construction
      long m2 = (long)p[i].imgs * 4;
      if (m1 > m1m) m1m = m1;
      if (m2 > m2m) m2m = m2;
      m2t += m2;
    }
    long m2l = mg ? m2t : m2m;
    size_t scr = (size_t)m1m * 1024;                         // P1 bytes
    if ((size_t)m2l * 8192 > scr) scr = (size_t)m2l * 8192;  // C2h (z=8) fp16
    if (gruB > scr) scr = gruB;
    size_t need = fixedEnd + ((scr + 255) & ~(size_t)255) +
                  (((size_t)m2l * 8192 + 255) & ~(size_t)255);  // P2
    if (need <= ws_size) {
      nch = n;
      merged = mg;
      for (int i = 0; i < n; ++i) plan[i] = p[i];
      m1max = m1m;
      m2launch = m2l;
    }
  }
  if (!nch) {
    diag_kernel<<<(out_size + 255) / 256, 256, 0, stream>>>(
        (float*)d_out, out_size, (float)((double)ws_size * 1e-6));
    return;
  }
  size_t scr1 = (size_t)m1max * 1024;
  if ((size_t)m2launch * 8192 > scr1) scr1 = (size_t)m2launch * 8192;
  if (gruB > scr1) scr1 = gruB;
  char* scr = alloc(scr1);
  h16* P1 = (h16*)scr;             // conv1 A
  h16* C2h = (h16*)scr;            // conv2 fp16 partials (alias, P1 dead)
  h16* giPart = (h16*)scr;         // gru fp16 partials (alias, after pool2)
  h16* ghPart = giPart + 2 * PS;
  h16* P2 = (h16*)alloc((size_t)m2launch * 8192);

  // ---- weight conversion ----
  Cvt8 cj;
  const float* srcs[8] = {ncw1, ecw1, ncw2, ecw2, nwih, nwhh, ewih, ewhh};
  h16* dsts[8] = {W1rn, W1re, W2rn, W2re, Wihn, Whhn, Wihe, Whhe};
  long sizes[8] = {1024 * 512, 1024 * 512, (long)512 * 4096, (long)512 * 4096,
                   1536 * 512, 1536 * 512, 1536 * 512, 1536 * 512};
  int perms[8] = {0, 0, 1, 1, 0, 0, 0, 0};
  long c = 0;
  for (int i = 0; i < 8; ++i) {
    cj.s[i] = srcs[i];
    cj.d[i] = dsts[i];
    cj.cum[i] = c;
    cj.perm[i] = perms[i];
    c += sizes[i];
  }
  cj.cum[8] = c;
  cvt8_kernel<<<(unsigned)((c / 4 + 255) / 256), 256, 0, stream>>>(cj);
  incid_kernel<<<16, 256, 0, stream>>>(eidx, elist, istride);

  // ---- CNN encoders: im2col -> fused conv1+pool (-> conv2 + pool2) ----
  long imgBase = 0;
  for (int ci = 0; ci < nch; ++ci) {
    const Chunk& K = plan[ci];
    long m1 = (long)K.imgs * 36;
    long m2 = (long)K.imgs * 4;
    int sw1 = (K.nNode * 36) >> 7;  // 0 => all edge (part1)
    int sw2 = (K.nNode * 4) >> 7;

    im2col1_kernel<<<(unsigned)K.imgs, 256, 0, stream>>>(node_lat, edge_lat,
                                                         K.nNode, K.e0, P1);

    GemmP g1 = {};
    g1.A[0] = P1;
    g1.Bt[0][0] = W1rn; g1.Bt[0][1] = W1re;
    g1.C[0] = P2 + (merged ? imgBase * 4 * 4096 : 0);
    g1.bias[0][0] = ncb1; g1.bias[0][1] = ecb1;
    g1.M = (int)m1; g1.N = 1024; g1.K = 512; g1.nkt = 16; g1.bmSwitch = sw1;
    gemm_bt<4, 1><<<(unsigned)((m1 >> 7) * 8), 256, 0, stream>>>(g1);
    imgBase += K.imgs;

    if (!merged) {
      GemmP g2 = {};
      g2.A[0] = P2;
      g2.Bt[0][0] = W2rn; g2.Bt[0][1] = W2re;
      g2.C[0] = C2h;
      g2.M = (int)m2; g2.N = 512; g2.K = 4096; g2.nkt = 16; g2.bmSwitch = sw2;
      gemm_bt<3, 1><<<dim3((unsigned)((m2 >> 7) * 4), 1, 8), 256, 0, stream>>>(g2);
      pool2_kernel<<<(unsigned)(K.imgs * 2), 256, 0, stream>>>(
          C2h, m2 * 512L, 8, ncb2, ecb2, K.nNode, K.e0, featc);
    }
  }
  if (merged) {  // one conv2 + one pool2 over all chunks
    GemmP g2 = {};
    g2.A[0] = P2;
    g2.Bt[0][0] = W2rn; g2.Bt[0][1] = W2re;
    g2.C[0] = C2h;
    g2.M = (int)m2launch; g2.N = 512; g2.K = 4096; g2.nkt = 16;
    g2.bmSwitch = 2;  // node rows 0..255
    gemm_bt<3, 1><<<dim3((unsigned)((m2launch >> 7) * 4), 1, 8), 256, 0,
                    stream>>>(g2);
    pool2_kernel<<<(unsigned)(2048 * 2), 256, 0, stream>>>(
        C2h, m2launch * 512L, 8, ncb2, ecb2, 64, 0, featc);
  }

  // ---- initial GRU (h = 0): gi fp16 partials (z=2) then combine ----
  {
    GemmP g = {};
    g.A[0] = featc;
    g.Bt[0][0] = Wihn; g.Bt[0][1] = Wihe;
    g.C[0] = giPart;
    g.M = 2176; g.N = 1536; g.K = 512; g.nkt = 8; g.bmSwitch = 1;
    gemm_bt<3, 1><<<dim3(17 * 12, 1, 2), 256, 0, stream>>>(g);
  }
  gru_init_kernel<<<1088, 256, 0, stream>>>(giPart, PS, nbih, ebih, nbhh, ebhh,
                                            h, hc);

  // ---- 2 message-passing iterations (ref's 3rd iteration output is dead) ----
  for (int it = 0; it < 2; ++it) {
    message_kernel<<<496, 256, 0, stream>>>(hc, eidx, wnp, wps, wpo, msgc,
                                            nm_e, istride);
    gather_kernel<<<64, 256, 0, stream>>>(nm_e, elist, msgc);
    GemmP g = {};
    g.A[0] = msgc; g.A[1] = hc;
    g.Bt[0][0] = Wihn; g.Bt[0][1] = Wihe;
    g.Bt[1][0] = Whhn; g.Bt[1][1] = Whhe;
    g.C[0] = giPart; g.C[1] = ghPart;
    g.M = 2176; g.N = 1536; g.K = 512; g.nkt = 8; g.bmSwitch = 1;
    gemm_bt<3, 2><<<dim3(17 * 12, 2, 2), 256, 0, stream>>>(g);
    gru_step_kernel<<<1088, 256, 0, stream>>>(
        giPart, ghPart, PS, nbih, ebih, nbhh, ebhh, h, hc,
        (it == 1) ? (float*)d_out : nullptr);
  }
}